// Round 6
// baseline (454.327 us; speedup 1.0000x reference)
//
#include <hip/hip_runtime.h>
#include <cstdint>
#include <cstddef>

typedef __bf16 bf16;
typedef __bf16 bf16x4 __attribute__((ext_vector_type(4)));
typedef __bf16 bf16x8 __attribute__((ext_vector_type(8)));
typedef float f32x4 __attribute__((ext_vector_type(4)));

// Problem: B=8, L=1024, S=1000 (pad 1024), GRAPH=512, LLM=4096, H=8, E=128, DKH=1024
// Inputs fp32. OUTPUT fp32.

__device__ __forceinline__ void gload_lds16(const void* g, void* l) {
    typedef __attribute__((address_space(1))) void gv;
    typedef __attribute__((address_space(3))) void lv;
    __builtin_amdgcn_global_load_lds((gv*)g, (lv*)l, 16, 0, 0);
}

// ---------------------------------------------------------------------------
// Fused fp32 -> bf16 cast for the 3 input tensors (grid.y picks the tensor).
// Elements >= n_in written as 0 (row padding for source/value S=1000 -> 1024).
// ---------------------------------------------------------------------------
__global__ __launch_bounds__(256) void cast3_f32_bf16(
    const float* __restrict__ in0, bf16* __restrict__ out0,
    const float* __restrict__ in1, bf16* __restrict__ out1,
    const float* __restrict__ in2, bf16* __restrict__ out2)
{
    const int which = blockIdx.y;
    const float* in = which == 0 ? in0 : which == 1 ? in1 : in2;
    bf16* out       = which == 0 ? out0 : which == 1 ? out1 : out2;
    const size_t n_in = which == 0 ? (size_t)8192 * 512 : (size_t)1000 * 4096;

    const size_t i = ((size_t)blockIdx.x * 256 + threadIdx.x) * 8;
    f32x4 a = (f32x4){0.f, 0.f, 0.f, 0.f};
    f32x4 b = (f32x4){0.f, 0.f, 0.f, 0.f};
    if (i < n_in) {
        a = *(const f32x4*)(in + i);
        b = *(const f32x4*)(in + i + 4);
    }
    bf16x8 o;
    o[0] = (bf16)a[0]; o[1] = (bf16)a[1]; o[2] = (bf16)a[2]; o[3] = (bf16)a[3];
    o[4] = (bf16)b[0]; o[5] = (bf16)b[1]; o[6] = (bf16)b[2]; o[7] = (bf16)b[3];
    *(bf16x8*)(out + i) = o;
}

// ---------------------------------------------------------------------------
// Fused transpose+cast for all 4 weights (one launch; flat grid 12800).
// in fp32 [R,C] -> out bf16 [C,R].
// ---------------------------------------------------------------------------
__global__ __launch_bounds__(256) void transpose4(
    const float* __restrict__ Wq, bf16* __restrict__ WqT,
    const float* __restrict__ Wk, bf16* __restrict__ WkT,
    const float* __restrict__ Wv, bf16* __restrict__ WvT,
    const float* __restrict__ Wo, bf16* __restrict__ WoT)
{
    int id = blockIdx.x;
    const float* in; bf16* out; int R, C, bx, by;
    if (id < 512)       { in = Wq; out = WqT; R = 512;  C = 1024; bx = id % 32;  by = id / 32; }
    else if (id < 4608) { id -= 512;  in = Wk; out = WkT; R = 4096; C = 1024; bx = id % 32;  by = id / 32; }
    else if (id < 8704) { id -= 4608; in = Wv; out = WvT; R = 4096; C = 1024; bx = id % 32;  by = id / 32; }
    else                { id -= 8704; in = Wo; out = WoT; R = 1024; C = 4096; bx = id % 128; by = id / 128; }

    __shared__ bf16 tile[32][33];
    const int tx = threadIdx.x & 31, ty = threadIdx.x >> 5;
    const int c0 = bx * 32, r0 = by * 32;
    #pragma unroll
    for (int i = ty; i < 32; i += 8)
        tile[i][tx] = (bf16)in[(size_t)(r0 + i) * C + (c0 + tx)];
    __syncthreads();
    #pragma unroll
    for (int i = ty; i < 32; i += 8)
        out[(size_t)(c0 + i) * R + (r0 + tx)] = tile[tx][i];
}

// ---------------------------------------------------------------------------
// GEMM: C[M,N] = A[M,K] @ Bt[N,K]^T + bias[N]; A,Bt bf16, bias fp32, fp32 acc.
// 256 thr = 4 waves; 128x128 C-tile; 2x2 waves of 64x64 (4x4 MFMA 16x16x32).
// r6: BK=64 (32 MFMA per barrier-pair, half the barrier-drain stalls) with
// XOR-swizzled LDS: [128][64] bf16 rows are 128 B = the 16-way-conflict trap,
// so stage with pre-swizzled GLOBAL chunk (chunk ^= row&7; LDS dest linear,
// required by global_load_lds) and XOR the same on the ds_read -> 2-way max.
// XCD rectangle swizzle: each XCD's contiguous work = 8x8 superblock of
// tiles (8 A-panels + 8 B-panels = 4 MB = one XCD L2); default round-robin
// scattered 24 MB inputs into 77 MB of L2-miss FETCH (r5 counters).
// MFMA operands SWAPPED (mfma(bfr, af)): lane owns row m = cl, 4 consecutive
// cols -> f32x4/bf16x4 stores. fp32 path nontemporal (write-once output).
// ---------------------------------------------------------------------------
__global__ __launch_bounds__(256, 3) void gemm_bt(
    const bf16* __restrict__ A, const bf16* __restrict__ Bt,
    const float* __restrict__ bias, void* __restrict__ Cv,
    int M, int N, int K, int lda, int ldb, int ldc, int outF32)
{
    __shared__ __align__(16) bf16 As[128 * 64];   // 16 KB
    __shared__ __align__(16) bf16 Bs[128 * 64];   // 16 KB

    const int tid = threadIdx.x;
    const int w = tid >> 6, ln = tid & 63;

    // XCD rectangle swizzle (bijective when gx%8==0 && gy%8==0).
    const int gx = gridDim.x, gy = gridDim.y;
    int bm, bn;
    if (((gx & 7) | (gy & 7)) == 0) {
        const int orig = blockIdx.y * gx + blockIdx.x;
        const int xcd = orig & 7, t = orig >> 3;
        const int nsb_x = gx >> 3;
        const int s = xcd + 8 * (t >> 6);       // global superblock id
        const int win = t & 63;                 // position within 8x8 sb
        bm = (s / nsb_x) * 8 + (win >> 3);
        bn = (s % nsb_x) * 8 + (win & 7);
    } else {
        bm = blockIdx.y; bn = blockIdx.x;
    }

    const int wm = (w >> 1) * 64, wn = (w & 1) * 64;
    const int rgrp = ln >> 4, cl = ln & 15;

    f32x4 acc[4][4];
    #pragma unroll
    for (int mt = 0; mt < 4; ++mt)
        #pragma unroll
        for (int nt = 0; nt < 4; ++nt)
            acc[mt][nt] = (f32x4){0.f, 0.f, 0.f, 0.f};

    for (int k0 = 0; k0 < K; k0 += 64) {
        // Stage [128 rows][64 k]: row = t2>>3 (8 chunks of 16B per row);
        // global chunk pre-swizzled by row&7; LDS dest linear (= t2*16).
        #pragma unroll
        for (int j = 0; j < 4; ++j) {
            const int t2 = tid + 256 * j;
            const int row = t2 >> 3;
            const int ch = (t2 & 7) ^ (row & 7);
            int arow = bm * 128 + row;
            if (arow > M - 1) arow = M - 1;
            gload_lds16(A + (size_t)arow * lda + k0 + ch * 8,
                        (char*)As + j * 4096 + w * 1024);
            const int brow = bn * 128 + row;
            gload_lds16(Bt + (size_t)brow * ldb + k0 + ch * 8,
                        (char*)Bs + j * 4096 + w * 1024);
        }
        __syncthreads();

        #pragma unroll
        for (int kk = 0; kk < 2; ++kk) {
            bf16x8 af[4], bfr[4];
            #pragma unroll
            for (int mt = 0; mt < 4; ++mt) {
                const int row = wm + mt * 16 + cl;
                const int ch = (kk * 4 + rgrp) ^ (row & 7);
                af[mt] = *(const bf16x8*)(As + row * 64 + ch * 8);
            }
            #pragma unroll
            for (int nt = 0; nt < 4; ++nt) {
                const int row = wn + nt * 16 + cl;
                const int ch = (kk * 4 + rgrp) ^ (row & 7);
                bfr[nt] = *(const bf16x8*)(Bs + row * 64 + ch * 8);
            }
            // Swapped operands: D row = af's m (cl), cols = bfr's n.
            #pragma unroll
            for (int mt = 0; mt < 4; ++mt)
                #pragma unroll
                for (int nt = 0; nt < 4; ++nt)
                    acc[mt][nt] = __builtin_amdgcn_mfma_f32_16x16x32_bf16(
                        bfr[nt], af[mt], acc[mt][nt], 0, 0, 0);
        }
        __syncthreads();
    }

    // Lane (rgrp,cl), tile (mt,nt): row m = cl, cols n = rgrp*4 + reg.
    #pragma unroll
    for (int nt = 0; nt < 4; ++nt) {
        const int col0 = bn * 128 + wn + nt * 16 + rgrp * 4;
        const f32x4 bv4 = bias ? *(const f32x4*)(bias + col0)
                               : (f32x4){0.f, 0.f, 0.f, 0.f};
        #pragma unroll
        for (int mt = 0; mt < 4; ++mt) {
            const int row = bm * 128 + wm + mt * 16 + cl;
            if (row < M) {
                const f32x4 v = acc[mt][nt] + bv4;
                if (outF32) {
                    __builtin_nontemporal_store(
                        v, (f32x4*)((float*)Cv + (size_t)row * ldc + col0));
                } else {
                    bf16x4 h;
                    h[0] = (bf16)v[0]; h[1] = (bf16)v[1];
                    h[2] = (bf16)v[2]; h[3] = (bf16)v[3];
                    *(bf16x4*)((bf16*)Cv + (size_t)row * ldc + col0) = h;
                }
            }
        }
    }
}

// ---------------------------------------------------------------------------
// Fused K+V projection: 64x64-tile GEMM, BK=64; blockIdx.z selects operand
// set (z=0: K = src@WkT -> Kb; z=1: V -> Vt TRANSPOSED). M=N=1024, K=4096.
// ---------------------------------------------------------------------------
__global__ __launch_bounds__(256, 4) void gemm_kv(
    const bf16* __restrict__ A0, const bf16* __restrict__ Bt0,
    const float* __restrict__ b0, bf16* __restrict__ C0,
    const bf16* __restrict__ A1, const bf16* __restrict__ Bt1,
    const float* __restrict__ b1, bf16* __restrict__ C1)
{
    const int sel = blockIdx.z;
    const bf16* A  = sel ? A1 : A0;
    const bf16* Bt = sel ? Bt1 : Bt0;
    const float* bias = sel ? b1 : b0;
    bf16* Cv = sel ? C1 : C0;
    const int transC = sel;
    const int K = 4096, lda = 4096, ldb = 4096, ldc = 1024;

    __shared__ __align__(16) bf16 As[64 * 64];
    __shared__ __align__(16) bf16 Bs[64 * 64];

    const int tid = threadIdx.x;
    const int w = tid >> 6, ln = tid & 63;
    const int bm = blockIdx.y, bn = blockIdx.x;
    const int wm = (w >> 1) * 32, wn = (w & 1) * 32;
    const int rgrp = ln >> 4, cl = ln & 15;

    f32x4 acc[2][2];
    #pragma unroll
    for (int mt = 0; mt < 2; ++mt)
        #pragma unroll
        for (int nt = 0; nt < 2; ++nt)
            acc[mt][nt] = (f32x4){0.f, 0.f, 0.f, 0.f};

    for (int k0 = 0; k0 < K; k0 += 64) {
        #pragma unroll
        for (int j = 0; j < 2; ++j) {
            const int arow = bm * 64 + j * 32 + w * 8 + (ln >> 3);
            const bf16* ag = A + (size_t)arow * lda + k0 + (ln & 7) * 8;
            gload_lds16(ag, (char*)As + j * 4096 + w * 1024);
            const int brow = bn * 64 + j * 32 + w * 8 + (ln >> 3);
            const bf16* bg = Bt + (size_t)brow * ldb + k0 + (ln & 7) * 8;
            gload_lds16(bg, (char*)Bs + j * 4096 + w * 1024);
        }
        __syncthreads();

        bf16x8 af[2][2], bfr[2][2];
        #pragma unroll
        for (int mt = 0; mt < 2; ++mt)
            #pragma unroll
            for (int kk = 0; kk < 2; ++kk)
                af[mt][kk] = *(const bf16x8*)(As + (wm + mt * 16 + cl) * 64 + kk * 32 + rgrp * 8);
        #pragma unroll
        for (int nt = 0; nt < 2; ++nt)
            #pragma unroll
            for (int kk = 0; kk < 2; ++kk)
                bfr[nt][kk] = *(const bf16x8*)(Bs + (wn + nt * 16 + cl) * 64 + kk * 32 + rgrp * 8);
        #pragma unroll
        for (int mt = 0; mt < 2; ++mt)
            #pragma unroll
            for (int nt = 0; nt < 2; ++nt)
                #pragma unroll
                for (int kk = 0; kk < 2; ++kk)
                    acc[mt][nt] = __builtin_amdgcn_mfma_f32_16x16x32_bf16(
                        af[mt][kk], bfr[nt][kk], acc[mt][nt], 0, 0, 0);
        __syncthreads();
    }

    #pragma unroll
    for (int nt = 0; nt < 2; ++nt) {
        const int col = bn * 64 + wn + nt * 16 + cl;
        const float bvv = bias[col];
        #pragma unroll
        for (int mt = 0; mt < 2; ++mt) {
            #pragma unroll
            for (int reg = 0; reg < 4; ++reg) {
                const int row = bm * 64 + wm + mt * 16 + rgrp * 4 + reg;
                const float v = acc[mt][nt][reg] + bvv;
                const size_t idx = transC ? (size_t)col * ldc + row
                                          : (size_t)row * ldc + col;
                Cv[idx] = (bf16)v;
            }
        }
    }
}

// ---------------------------------------------------------------------------
// Flash attention v5 + setprio (T5): block-level LDS staging of K/V shared
// by 4 waves; double-buffered, one barrier per s-tile; swapped QK; defer-
// rescale; wave-private P roundtrip. (r4 WIN structure, unchanged otherwise.)
// ---------------------------------------------------------------------------
__global__ __launch_bounds__(256) void flash_attn(
    const bf16* __restrict__ Q, const bf16* __restrict__ Kb,
    const bf16* __restrict__ Vt, bf16* __restrict__ O)
{
    const int tid = threadIdx.x;
    const int w = tid >> 6, ln = tid & 63;
    const int b = blockIdx.x >> 3, h = blockIdx.x & 7;
    const int l0 = blockIdx.y * 128 + w * 32;
    const int rgrp = ln >> 4, cl = ln & 15;
    const float sl2 = 0.08838834764831845f * 1.44269504088896340736f;  // scale*log2e

    __shared__ __align__(16) bf16 Ks[2][32 * 128];   // 16 KB (2 buf)
    __shared__ __align__(16) bf16 Vs[2][128 * 32];   // 16 KB (2 buf)
    __shared__ __align__(16) bf16 Pl[4][2][16 * 40]; // 10 KB, per wave per m

    bf16x8 qf[2][4];
    #pragma unroll
    for (int m = 0; m < 2; ++m) {
        const bf16* qp = Q + (size_t)(b * 1024 + l0 + m * 16 + cl) * 1024 + h * 128 + rgrp * 8;
        #pragma unroll
        for (int kk = 0; kk < 4; ++kk) qf[m][kk] = *(const bf16x8*)(qp + kk * 32);
    }

    f32x4 o[2][8];
    #pragma unroll
    for (int m = 0; m < 2; ++m)
        #pragma unroll
        for (int nt = 0; nt < 8; ++nt) o[m][nt] = (f32x4){0.f, 0.f, 0.f, 0.f};
    float m_[2] = {-1e30f, -1e30f};
    float l_[2] = {0.f, 0.f};

    auto stage = [&](int bi, int t) {
        const int s0 = t * 32;
        #pragma unroll
        for (int c = 0; c < 2; ++c) {
            {   // K: row bytes 256 (16 chunks of 16B); chunk ^= (row&7)
                const int r = c * 16 + w * 4 + (ln >> 4);
                const int e = ((ln & 15) ^ (r & 7)) << 3;
                gload_lds16(Kb + (size_t)(s0 + r) * 1024 + h * 128 + e,
                            (char*)Ks[bi] + c * 4096 + w * 1024);
            }
            {   // V^T: row bytes 64 (4 chunks of 16B); chunk ^= (row&3)
                const int r = c * 64 + w * 16 + (ln >> 2);
                const int sc = ((ln & 3) ^ (r & 3)) << 3;
                gload_lds16(Vt + (size_t)(h * 128 + r) * 1024 + s0 + sc,
                            (char*)Vs[bi] + c * 4096 + w * 1024);
            }
        }
    };

    stage(0, 0);

    for (int t = 0; t < 32; ++t) {
        __syncthreads();  // stage(t) landed; buf[(t+1)&1] free
        if (t < 31) stage((t + 1) & 1, t + 1);  // flies under this tile's compute
        const int bi = t & 1;
        const int s0 = t * 32;
        const bf16* Kt = Ks[bi];
        const bf16* Vtl = Vs[bi];

        bf16x8 kf[2][4];
        #pragma unroll
        for (int half = 0; half < 2; ++half) {
            const int row = half * 16 + cl;
            #pragma unroll
            for (int kk = 0; kk < 4; ++kk) {
                const int pos = (kk * 4 + rgrp) ^ (row & 7);
                kf[half][kk] = *(const bf16x8*)((const char*)Kt + row * 256 + pos * 16);
            }
        }

        f32x4 st[2][2];
        __builtin_amdgcn_s_setprio(1);
        #pragma unroll
        for (int m = 0; m < 2; ++m)
            #pragma unroll
            for (int half = 0; half < 2; ++half) {
                f32x4 sc = (f32x4){0.f, 0.f, 0.f, 0.f};
                #pragma unroll
                for (int kk = 0; kk < 4; ++kk)
                    sc = __builtin_amdgcn_mfma_f32_16x16x32_bf16(
                        kf[half][kk], qf[m][kk], sc, 0, 0, 0);
                st[m][half] = sc;
            }
        __builtin_amdgcn_s_setprio(0);

        #pragma unroll
        for (int m = 0; m < 2; ++m) {
            float z[8];
            #pragma unroll
            for (int half = 0; half < 2; ++half)
                #pragma unroll
                for (int reg = 0; reg < 4; ++reg) {
                    const int sg = s0 + half * 16 + rgrp * 4 + reg;
                    z[half * 4 + reg] = (sg < 1000) ? st[m][half][reg] * sl2 : -1e30f;
                }
            float mx = fmaxf(fmaxf(fmaxf(z[0], z[1]), fmaxf(z[2], z[3])),
                             fmaxf(fmaxf(z[4], z[5]), fmaxf(z[6], z[7])));
            mx = fmaxf(mx, __shfl_xor(mx, 16));
            mx = fmaxf(mx, __shfl_xor(mx, 32));
            if (__any(mx > m_[m] + 8.0f)) {
                const float mnew = fmaxf(m_[m], mx);
                const float alpha = __builtin_amdgcn_exp2f(m_[m] - mnew);
                m_[m] = mnew;
                l_[m] *= alpha;
                #pragma unroll
                for (int reg = 0; reg < 4; ++reg) {
                    const float ar = __shfl(alpha, rgrp * 4 + reg);
                    #pragma unroll
                    for (int nt = 0; nt < 8; ++nt) o[m][nt][reg] *= ar;
                }
            }
            float p[8];
            float rs = 0.f;
            #pragma unroll
            for (int i = 0; i < 8; ++i) {
                p[i] = __builtin_amdgcn_exp2f(z[i] - m_[m]);
                rs += p[i];
            }
            rs += __shfl_xor(rs, 16);
            rs += __shfl_xor(rs, 32);
            l_[m] += rs;
            #pragma unroll
            for (int half = 0; half < 2; ++half) {
                bf16x4 pk;
                #pragma unroll
                for (int reg = 0; reg < 4; ++reg) pk[reg] = (bf16)p[half * 4 + reg];
                *(bf16x4*)(&Pl[w][m][cl * 40 + half * 16 + rgrp * 4]) = pk;
            }
        }

        bf16x8 vf[8];
        #pragma unroll
        for (int nt = 0; nt < 8; ++nt) {
            const int row = nt * 16 + cl;
            const int pos = rgrp ^ (row & 3);
            vf[nt] = *(const bf16x8*)((const char*)Vtl + row * 64 + pos * 16);
        }

        __builtin_amdgcn_s_setprio(1);
        #pragma unroll
        for (int m = 0; m < 2; ++m) {
            const bf16x8 pa = *(const bf16x8*)(&Pl[w][m][cl * 40 + rgrp * 8]);
            #pragma unroll
            for (int nt = 0; nt < 8; ++nt)
                o[m][nt] = __builtin_amdgcn_mfma_f32_16x16x32_bf16(
                    pa, vf[nt], o[m][nt], 0, 0, 0);
        }
        __builtin_amdgcn_s_setprio(0);
    }

    #pragma unroll
    for (int m = 0; m < 2; ++m) {
        #pragma unroll
        for (int reg = 0; reg < 4; ++reg) {
            const float inv = __builtin_amdgcn_rcpf(__shfl(l_[m], rgrp * 4 + reg));
            const int row = l0 + m * 16 + rgrp * 4 + reg;
            #pragma unroll
            for (int nt = 0; nt < 8; ++nt) {
                const int col = h * 128 + nt * 16 + cl;
                O[(size_t)(b * 1024 + row) * 1024 + col] = (bf16)(o[m][nt][reg] * inv);
            }
        }
    }
}

// ---------------------------------------------------------------------------
extern "C" void kernel_launch(void* const* d_in, const int* in_sizes, int n_in,
                              void* d_out, int out_size, void* d_ws, size_t ws_size,
                              hipStream_t stream)
{
    const float* target = (const float*)d_in[0];  // [8192, 512]
    const float* source = (const float*)d_in[1];  // [1000, 4096]
    const float* value  = (const float*)d_in[2];  // [1000, 4096]
    const float* Wq = (const float*)d_in[3];      // [512, 1024]
    const float* bq = (const float*)d_in[4];
    const float* Wk = (const float*)d_in[5];      // [4096, 1024]
    const float* bk = (const float*)d_in[6];
    const float* Wv = (const float*)d_in[7];      // [4096, 1024]
    const float* bv = (const float*)d_in[8];
    const float* Wo = (const float*)d_in[9];      // [1024, 4096]
    const float* bo = (const float*)d_in[10];

    // d_out is fp32 [8192,4096] = 128 MB. Scratch whose lifetime ends before
    // the final GEMM lives there (61 MB). AO + WoT (read by final GEMM) -> d_ws.
    char* po = (char*)d_out;
    size_t off = 0;
    bf16* tgt_b = (bf16*)(po + off); off += (size_t)8192 * 512 * 2;   //  8 MB
    bf16* src_b = (bf16*)(po + off); off += (size_t)1024 * 4096 * 2;  //  8 MB
    bf16* val_b = (bf16*)(po + off); off += (size_t)1024 * 4096 * 2;  //  8 MB
    bf16* WqT   = (bf16*)(po + off); off += (size_t)1024 * 512 * 2;   //  1 MB
    bf16* WkT   = (bf16*)(po + off); off += (size_t)1024 * 4096 * 2;  //  8 MB
    bf16* WvT   = (bf16*)(po + off); off += (size_t)1024 * 4096 * 2;  //  8 MB
    bf16* Qb    = (bf16*)(po + off); off += (size_t)8192 * 1024 * 2;  // 16 MB
    bf16* Kb    = (bf16*)(po + off); off += (size_t)1024 * 1024 * 2;  //  2 MB
    bf16* Vt    = (bf16*)(po + off); off += (size_t)1024 * 1024 * 2;  //  2 MB = 61 MB
    char* ws = (char*)d_ws;
    bf16* AO  = (bf16*)ws;                                   // 16 MB
    bf16* WoT = (bf16*)(ws + (size_t)8192 * 1024 * 2);       //  8 MB (24 MB d_ws)

    // Fused casts: grid.y = {target, source, value}.
    cast3_f32_bf16<<<dim3(2048, 3), 256, 0, stream>>>(
        target, tgt_b, source, src_b, value, val_b);

    // Fused weight transposes (one launch, 12800 blocks).
    transpose4<<<12800, 256, 0, stream>>>(Wq, WqT, Wk, WkT, Wv, WvT, Wo, WoT);

    // Q = target @ Wq + bq   [8192,1024] bf16
    gemm_bt<<<dim3(8, 64), 256, 0, stream>>>(tgt_b, WqT, bq, Qb, 8192, 1024, 512, 512, 512, 1024, 0);
    // K = source @ Wk + bk -> Kb;  V^T = (value @ Wv + bv)^T -> Vt  (fused)
    gemm_kv<<<dim3(16, 16, 2), 256, 0, stream>>>(
        src_b, WkT, bk, Kb, val_b, WvT, bv, Vt);

    // attention -> AO [8192,1024] bf16
    flash_attn<<<dim3(64, 8), 256, 0, stream>>>(Qb, Kb, Vt, AO);

    // out = AO @ Wo + bo -> d_out FP32 [8192,4096] (nt stores; full overwrite)
    gemm_bt<<<dim3(32, 64), 256, 0, stream>>>(AO, WoT, bo, d_out, 8192, 4096, 1024, 1024, 1024, 4096, 1);

    (void)in_sizes; (void)n_in; (void)out_size; (void)ws_size;
}

// Round 7
// 404.851 us; speedup vs baseline: 1.1222x; 1.1222x over previous
//
#include <hip/hip_runtime.h>
#include <cstdint>
#include <cstddef>

typedef __bf16 bf16;
typedef __bf16 bf16x4 __attribute__((ext_vector_type(4)));
typedef __bf16 bf16x8 __attribute__((ext_vector_type(8)));
typedef float f32x4 __attribute__((ext_vector_type(4)));

// Problem: B=8, L=1024, S=1000 (pad 1024), GRAPH=512, LLM=4096, H=8, E=128, DKH=1024
// Inputs fp32. OUTPUT fp32.

__device__ __forceinline__ void gload_lds16(const void* g, void* l) {
    typedef __attribute__((address_space(1))) void gv;
    typedef __attribute__((address_space(3))) void lv;
    __builtin_amdgcn_global_load_lds((gv*)g, (lv*)l, 16, 0, 0);
}

// ---------------------------------------------------------------------------
// Fused fp32 -> bf16 cast for the 3 input tensors (grid.y picks the tensor).
// Elements >= n_in written as 0 (row padding for source/value S=1000 -> 1024).
// ---------------------------------------------------------------------------
__global__ __launch_bounds__(256) void cast3_f32_bf16(
    const float* __restrict__ in0, bf16* __restrict__ out0,
    const float* __restrict__ in1, bf16* __restrict__ out1,
    const float* __restrict__ in2, bf16* __restrict__ out2)
{
    const int which = blockIdx.y;
    const float* in = which == 0 ? in0 : which == 1 ? in1 : in2;
    bf16* out       = which == 0 ? out0 : which == 1 ? out1 : out2;
    const size_t n_in = which == 0 ? (size_t)8192 * 512 : (size_t)1000 * 4096;

    const size_t i = ((size_t)blockIdx.x * 256 + threadIdx.x) * 8;
    f32x4 a = (f32x4){0.f, 0.f, 0.f, 0.f};
    f32x4 b = (f32x4){0.f, 0.f, 0.f, 0.f};
    if (i < n_in) {
        a = *(const f32x4*)(in + i);
        b = *(const f32x4*)(in + i + 4);
    }
    bf16x8 o;
    o[0] = (bf16)a[0]; o[1] = (bf16)a[1]; o[2] = (bf16)a[2]; o[3] = (bf16)a[3];
    o[4] = (bf16)b[0]; o[5] = (bf16)b[1]; o[6] = (bf16)b[2]; o[7] = (bf16)b[3];
    *(bf16x8*)(out + i) = o;
}

// ---------------------------------------------------------------------------
// Fused transpose+cast for all 4 weights (one launch; flat grid 12800).
// in fp32 [R,C] -> out bf16 [C,R].
// ---------------------------------------------------------------------------
__global__ __launch_bounds__(256) void transpose4(
    const float* __restrict__ Wq, bf16* __restrict__ WqT,
    const float* __restrict__ Wk, bf16* __restrict__ WkT,
    const float* __restrict__ Wv, bf16* __restrict__ WvT,
    const float* __restrict__ Wo, bf16* __restrict__ WoT)
{
    int id = blockIdx.x;
    const float* in; bf16* out; int R, C, bx, by;
    if (id < 512)       { in = Wq; out = WqT; R = 512;  C = 1024; bx = id % 32;  by = id / 32; }
    else if (id < 4608) { id -= 512;  in = Wk; out = WkT; R = 4096; C = 1024; bx = id % 32;  by = id / 32; }
    else if (id < 8704) { id -= 4608; in = Wv; out = WvT; R = 4096; C = 1024; bx = id % 32;  by = id / 32; }
    else                { id -= 8704; in = Wo; out = WoT; R = 1024; C = 4096; bx = id % 128; by = id / 128; }

    __shared__ bf16 tile[32][33];
    const int tx = threadIdx.x & 31, ty = threadIdx.x >> 5;
    const int c0 = bx * 32, r0 = by * 32;
    #pragma unroll
    for (int i = ty; i < 32; i += 8)
        tile[i][tx] = (bf16)in[(size_t)(r0 + i) * C + (c0 + tx)];
    __syncthreads();
    #pragma unroll
    for (int i = ty; i < 32; i += 8)
        out[(size_t)(c0 + i) * R + (r0 + tx)] = tile[tx][i];
}

// ---------------------------------------------------------------------------
// GEMM: C[M,N] = A[M,K] @ Bt[N,K]^T + bias[N]; A,Bt bf16, bias fp32, fp32 acc.
// 256 thr = 4 waves; 128x128 C-tile; 2x2 waves of 64x64 (4x4 MFMA 16x16x32).
// BK=64 (32 MFMA per barrier-pair) + XOR-swizzled LDS (pre-swizzled global
// chunk, linear dest, XOR on ds_read -> 2-way max). XCD rectangle swizzle
// (8x8 tile superblock per XCD = 4 MB = one XCD L2). Swapped MFMA operands:
// lane owns row m = cl, 4 consecutive cols -> f32x4/bf16x4 stores; fp32 path
// nontemporal (write-once output). [r6 WIN: final GEMM left top-5]
// ---------------------------------------------------------------------------
__global__ __launch_bounds__(256, 3) void gemm_bt(
    const bf16* __restrict__ A, const bf16* __restrict__ Bt,
    const float* __restrict__ bias, void* __restrict__ Cv,
    int M, int N, int K, int lda, int ldb, int ldc, int outF32)
{
    __shared__ __align__(16) bf16 As[128 * 64];   // 16 KB
    __shared__ __align__(16) bf16 Bs[128 * 64];   // 16 KB

    const int tid = threadIdx.x;
    const int w = tid >> 6, ln = tid & 63;

    // XCD rectangle swizzle (bijective when gx%8==0 && gy%8==0).
    const int gx = gridDim.x, gy = gridDim.y;
    int bm, bn;
    if (((gx & 7) | (gy & 7)) == 0) {
        const int orig = blockIdx.y * gx + blockIdx.x;
        const int xcd = orig & 7, t = orig >> 3;
        const int nsb_x = gx >> 3;
        const int s = xcd + 8 * (t >> 6);       // global superblock id
        const int win = t & 63;                 // position within 8x8 sb
        bm = (s / nsb_x) * 8 + (win >> 3);
        bn = (s % nsb_x) * 8 + (win & 7);
    } else {
        bm = blockIdx.y; bn = blockIdx.x;
    }

    const int wm = (w >> 1) * 64, wn = (w & 1) * 64;
    const int rgrp = ln >> 4, cl = ln & 15;

    f32x4 acc[4][4];
    #pragma unroll
    for (int mt = 0; mt < 4; ++mt)
        #pragma unroll
        for (int nt = 0; nt < 4; ++nt)
            acc[mt][nt] = (f32x4){0.f, 0.f, 0.f, 0.f};

    for (int k0 = 0; k0 < K; k0 += 64) {
        #pragma unroll
        for (int j = 0; j < 4; ++j) {
            const int t2 = tid + 256 * j;
            const int row = t2 >> 3;
            const int ch = (t2 & 7) ^ (row & 7);
            int arow = bm * 128 + row;
            if (arow > M - 1) arow = M - 1;
            gload_lds16(A + (size_t)arow * lda + k0 + ch * 8,
                        (char*)As + j * 4096 + w * 1024);
            const int brow = bn * 128 + row;
            gload_lds16(Bt + (size_t)brow * ldb + k0 + ch * 8,
                        (char*)Bs + j * 4096 + w * 1024);
        }
        __syncthreads();

        #pragma unroll
        for (int kk = 0; kk < 2; ++kk) {
            bf16x8 af[4], bfr[4];
            #pragma unroll
            for (int mt = 0; mt < 4; ++mt) {
                const int row = wm + mt * 16 + cl;
                const int ch = (kk * 4 + rgrp) ^ (row & 7);
                af[mt] = *(const bf16x8*)(As + row * 64 + ch * 8);
            }
            #pragma unroll
            for (int nt = 0; nt < 4; ++nt) {
                const int row = wn + nt * 16 + cl;
                const int ch = (kk * 4 + rgrp) ^ (row & 7);
                bfr[nt] = *(const bf16x8*)(Bs + row * 64 + ch * 8);
            }
            #pragma unroll
            for (int mt = 0; mt < 4; ++mt)
                #pragma unroll
                for (int nt = 0; nt < 4; ++nt)
                    acc[mt][nt] = __builtin_amdgcn_mfma_f32_16x16x32_bf16(
                        bfr[nt], af[mt], acc[mt][nt], 0, 0, 0);
        }
        __syncthreads();
    }

    #pragma unroll
    for (int nt = 0; nt < 4; ++nt) {
        const int col0 = bn * 128 + wn + nt * 16 + rgrp * 4;
        const f32x4 bv4 = bias ? *(const f32x4*)(bias + col0)
                               : (f32x4){0.f, 0.f, 0.f, 0.f};
        #pragma unroll
        for (int mt = 0; mt < 4; ++mt) {
            const int row = bm * 128 + wm + mt * 16 + cl;
            if (row < M) {
                const f32x4 v = acc[mt][nt] + bv4;
                if (outF32) {
                    __builtin_nontemporal_store(
                        v, (f32x4*)((float*)Cv + (size_t)row * ldc + col0));
                } else {
                    bf16x4 h;
                    h[0] = (bf16)v[0]; h[1] = (bf16)v[1];
                    h[2] = (bf16)v[2]; h[3] = (bf16)v[3];
                    *(bf16x4*)((bf16*)Cv + (size_t)row * ldc + col0) = h;
                }
            }
        }
    }
}

// ---------------------------------------------------------------------------
// Fused K+V projection: 64x64-tile GEMM, BK=64; blockIdx.z selects operand
// set (z=0: K -> Kb; z=1: V -> Vt TRANSPOSED). M=N=1024, K=4096.
// r7: XOR chunk-swizzle on the [64][64] LDS tiles — 128 B row stride put all
// 16 cl lanes in ONE bank (16-way conflict, G4 trap); pre-swizzled global
// source + XOR'd ds_read makes it 2-way (free).
// ---------------------------------------------------------------------------
__global__ __launch_bounds__(256, 4) void gemm_kv(
    const bf16* __restrict__ A0, const bf16* __restrict__ Bt0,
    const float* __restrict__ b0, bf16* __restrict__ C0,
    const bf16* __restrict__ A1, const bf16* __restrict__ Bt1,
    const float* __restrict__ b1, bf16* __restrict__ C1)
{
    const int sel = blockIdx.z;
    const bf16* A  = sel ? A1 : A0;
    const bf16* Bt = sel ? Bt1 : Bt0;
    const float* bias = sel ? b1 : b0;
    bf16* Cv = sel ? C1 : C0;
    const int transC = sel;
    const int K = 4096, lda = 4096, ldb = 4096, ldc = 1024;

    __shared__ __align__(16) bf16 As[64 * 64];
    __shared__ __align__(16) bf16 Bs[64 * 64];

    const int tid = threadIdx.x;
    const int w = tid >> 6, ln = tid & 63;
    const int bm = blockIdx.y, bn = blockIdx.x;
    const int wm = (w >> 1) * 32, wn = (w & 1) * 32;
    const int rgrp = ln >> 4, cl = ln & 15;

    f32x4 acc[2][2];
    #pragma unroll
    for (int mt = 0; mt < 2; ++mt)
        #pragma unroll
        for (int nt = 0; nt < 2; ++nt)
            acc[mt][nt] = (f32x4){0.f, 0.f, 0.f, 0.f};

    for (int k0 = 0; k0 < K; k0 += 64) {
        // Stage [64 rows][8 chunks of 16B]; global chunk pre-swizzled by
        // row&7 (LDS dest linear = t2*16, required by global_load_lds).
        #pragma unroll
        for (int j = 0; j < 2; ++j) {
            const int t2 = tid + 256 * j;
            const int row = t2 >> 3;
            const int ch = (t2 & 7) ^ (row & 7);
            const int arow = bm * 64 + row;
            gload_lds16(A + (size_t)arow * lda + k0 + ch * 8,
                        (char*)As + j * 4096 + w * 1024);
            const int brow = bn * 64 + row;
            gload_lds16(Bt + (size_t)brow * ldb + k0 + ch * 8,
                        (char*)Bs + j * 4096 + w * 1024);
        }
        __syncthreads();

        bf16x8 af[2][2], bfr[2][2];
        #pragma unroll
        for (int mt = 0; mt < 2; ++mt)
            #pragma unroll
            for (int kk = 0; kk < 2; ++kk) {
                const int row = wm + mt * 16 + cl;
                const int ch = (kk * 4 + rgrp) ^ (row & 7);
                af[mt][kk] = *(const bf16x8*)(As + row * 64 + ch * 8);
            }
        #pragma unroll
        for (int nt = 0; nt < 2; ++nt)
            #pragma unroll
            for (int kk = 0; kk < 2; ++kk) {
                const int row = wn + nt * 16 + cl;
                const int ch = (kk * 4 + rgrp) ^ (row & 7);
                bfr[nt][kk] = *(const bf16x8*)(Bs + row * 64 + ch * 8);
            }
        #pragma unroll
        for (int mt = 0; mt < 2; ++mt)
            #pragma unroll
            for (int nt = 0; nt < 2; ++nt)
                #pragma unroll
                for (int kk = 0; kk < 2; ++kk)
                    acc[mt][nt] = __builtin_amdgcn_mfma_f32_16x16x32_bf16(
                        af[mt][kk], bfr[nt][kk], acc[mt][nt], 0, 0, 0);
        __syncthreads();
    }

    #pragma unroll
    for (int nt = 0; nt < 2; ++nt) {
        const int col = bn * 64 + wn + nt * 16 + cl;
        const float bvv = bias[col];
        #pragma unroll
        for (int mt = 0; mt < 2; ++mt) {
            #pragma unroll
            for (int reg = 0; reg < 4; ++reg) {
                const int row = bm * 64 + wm + mt * 16 + rgrp * 4 + reg;
                const float v = acc[mt][nt][reg] + bvv;
                const size_t idx = transC ? (size_t)col * ldc + row
                                          : (size_t)row * ldc + col;
                Cv[idx] = (bf16)v;
            }
        }
    }
}

// ---------------------------------------------------------------------------
// Flash attention v6: LDS-staged K/V shared by 4 waves (r4 WIN base), now
// TWO s-tiles per barrier (quad buffer): barriers 32 -> 16, halving the
// vmcnt/lgkmcnt drain + 4-wave skew cost per tile, and giving the scheduler
// two independent tiles to interleave. setprio REMOVED (r6 regression;
// lockstep barrier structure = m190's harmful regime).
// Swapped QK (lane-local scores), defer-rescale (THR=8), wave-private P
// roundtrip, XOR-swizzled K/V tiles (pre-swizzled global src, linear dest).
// LDS: Ks 32K + Vs 32K + Pl 10K = 74 KB -> 2 blocks/CU.
// ---------------------------------------------------------------------------
__global__ __launch_bounds__(256) void flash_attn(
    const bf16* __restrict__ Q, const bf16* __restrict__ Kb,
    const bf16* __restrict__ Vt, bf16* __restrict__ O)
{
    const int tid = threadIdx.x;
    const int w = tid >> 6, ln = tid & 63;
    const int b = blockIdx.x >> 3, h = blockIdx.x & 7;
    const int l0 = blockIdx.y * 128 + w * 32;
    const int rgrp = ln >> 4, cl = ln & 15;
    const float sl2 = 0.08838834764831845f * 1.44269504088896340736f;  // scale*log2e

    __shared__ __align__(16) bf16 Ks[2][2][32 * 128];   // 32 KB (2 buf x 2 slot)
    __shared__ __align__(16) bf16 Vs[2][2][128 * 32];   // 32 KB
    __shared__ __align__(16) bf16 Pl[4][2][16 * 40];    // 10 KB, per wave per m

    bf16x8 qf[2][4];
    #pragma unroll
    for (int m = 0; m < 2; ++m) {
        const bf16* qp = Q + (size_t)(b * 1024 + l0 + m * 16 + cl) * 1024 + h * 128 + rgrp * 8;
        #pragma unroll
        for (int kk = 0; kk < 4; ++kk) qf[m][kk] = *(const bf16x8*)(qp + kk * 32);
    }

    f32x4 o[2][8];
    #pragma unroll
    for (int m = 0; m < 2; ++m)
        #pragma unroll
        for (int nt = 0; nt < 8; ++nt) o[m][nt] = (f32x4){0.f, 0.f, 0.f, 0.f};
    float m_[2] = {-1e30f, -1e30f};
    float l_[2] = {0.f, 0.f};

    // Stage s-tile t into (bi, slot). LDS dest linear; global source chunk
    // pre-swizzled so LDS[row][pos] = G[row][pos ^ (row & mask)].
    auto stage = [&](int bi, int slot, int t) {
        const int s0 = t * 32;
        #pragma unroll
        for (int c = 0; c < 2; ++c) {
            {   // K: row bytes 256 (16 chunks of 16B); chunk ^= (row&7)
                const int r = c * 16 + w * 4 + (ln >> 4);
                const int e = ((ln & 15) ^ (r & 7)) << 3;
                gload_lds16(Kb + (size_t)(s0 + r) * 1024 + h * 128 + e,
                            (char*)Ks[bi][slot] + c * 4096 + w * 1024);
            }
            {   // V^T: row bytes 64 (4 chunks of 16B); chunk ^= (row&3)
                const int r = c * 64 + w * 16 + (ln >> 2);
                const int sc = ((ln & 3) ^ (r & 3)) << 3;
                gload_lds16(Vt + (size_t)(h * 128 + r) * 1024 + s0 + sc,
                            (char*)Vs[bi][slot] + c * 4096 + w * 1024);
            }
        }
    };

    stage(0, 0, 0);
    stage(0, 1, 1);
    int buf = 0;

    for (int tp = 0; tp < 16; ++tp) {
        __syncthreads();  // pair (2tp, 2tp+1) landed; other buffer free
        if (tp < 15) {    // prefetch next pair under this pair's compute
            stage(buf ^ 1, 0, 2 * tp + 2);
            stage(buf ^ 1, 1, 2 * tp + 3);
        }

        #pragma unroll
        for (int u = 0; u < 2; ++u) {
            const int s0 = (2 * tp + u) * 32;
            const bf16* Kt = Ks[buf][u];
            const bf16* Vtl = Vs[buf][u];

            bf16x8 kf[2][4];
            #pragma unroll
            for (int half = 0; half < 2; ++half) {
                const int row = half * 16 + cl;
                #pragma unroll
                for (int kk = 0; kk < 4; ++kk) {
                    const int pos = (kk * 4 + rgrp) ^ (row & 7);
                    kf[half][kk] = *(const bf16x8*)((const char*)Kt + row * 256 + pos * 16);
                }
            }

            f32x4 st[2][2];
            #pragma unroll
            for (int m = 0; m < 2; ++m)
                #pragma unroll
                for (int half = 0; half < 2; ++half) {
                    f32x4 sc = (f32x4){0.f, 0.f, 0.f, 0.f};
                    #pragma unroll
                    for (int kk = 0; kk < 4; ++kk)
                        sc = __builtin_amdgcn_mfma_f32_16x16x32_bf16(
                            kf[half][kk], qf[m][kk], sc, 0, 0, 0);
                    st[m][half] = sc;
                }

            #pragma unroll
            for (int m = 0; m < 2; ++m) {
                float z[8];
                #pragma unroll
                for (int half = 0; half < 2; ++half)
                    #pragma unroll
                    for (int reg = 0; reg < 4; ++reg) {
                        const int sg = s0 + half * 16 + rgrp * 4 + reg;
                        z[half * 4 + reg] = (sg < 1000) ? st[m][half][reg] * sl2 : -1e30f;
                    }
                float mx = fmaxf(fmaxf(fmaxf(z[0], z[1]), fmaxf(z[2], z[3])),
                                 fmaxf(fmaxf(z[4], z[5]), fmaxf(z[6], z[7])));
                mx = fmaxf(mx, __shfl_xor(mx, 16));
                mx = fmaxf(mx, __shfl_xor(mx, 32));
                if (__any(mx > m_[m] + 8.0f)) {
                    const float mnew = fmaxf(m_[m], mx);
                    const float alpha = __builtin_amdgcn_exp2f(m_[m] - mnew);
                    m_[m] = mnew;
                    l_[m] *= alpha;
                    #pragma unroll
                    for (int reg = 0; reg < 4; ++reg) {
                        const float ar = __shfl(alpha, rgrp * 4 + reg);
                        #pragma unroll
                        for (int nt = 0; nt < 8; ++nt) o[m][nt][reg] *= ar;
                    }
                }
                float p[8];
                float rs = 0.f;
                #pragma unroll
                for (int i = 0; i < 8; ++i) {
                    p[i] = __builtin_amdgcn_exp2f(z[i] - m_[m]);
                    rs += p[i];
                }
                rs += __shfl_xor(rs, 16);
                rs += __shfl_xor(rs, 32);
                l_[m] += rs;
                #pragma unroll
                for (int half = 0; half < 2; ++half) {
                    bf16x4 pk;
                    #pragma unroll
                    for (int reg = 0; reg < 4; ++reg) pk[reg] = (bf16)p[half * 4 + reg];
                    *(bf16x4*)(&Pl[w][m][cl * 40 + half * 16 + rgrp * 4]) = pk;
                }
            }

            bf16x8 vf[8];
            #pragma unroll
            for (int nt = 0; nt < 8; ++nt) {
                const int row = nt * 16 + cl;
                const int pos = rgrp ^ (row & 3);
                vf[nt] = *(const bf16x8*)((const char*)Vtl + row * 64 + pos * 16);
            }

            #pragma unroll
            for (int m = 0; m < 2; ++m) {
                const bf16x8 pa = *(const bf16x8*)(&Pl[w][m][cl * 40 + rgrp * 8]);
                #pragma unroll
                for (int nt = 0; nt < 8; ++nt)
                    o[m][nt] = __builtin_amdgcn_mfma_f32_16x16x32_bf16(
                        pa, vf[nt], o[m][nt], 0, 0, 0);
            }
        }
        buf ^= 1;
    }

    #pragma unroll
    for (int m = 0; m < 2; ++m) {
        #pragma unroll
        for (int reg = 0; reg < 4; ++reg) {
            const float inv = __builtin_amdgcn_rcpf(__shfl(l_[m], rgrp * 4 + reg));
            const int row = l0 + m * 16 + rgrp * 4 + reg;
            #pragma unroll
            for (int nt = 0; nt < 8; ++nt) {
                const int col = h * 128 + nt * 16 + cl;
                O[(size_t)(b * 1024 + row) * 1024 + col] = (bf16)(o[m][nt][reg] * inv);
            }
        }
    }
}

// ---------------------------------------------------------------------------
extern "C" void kernel_launch(void* const* d_in, const int* in_sizes, int n_in,
                              void* d_out, int out_size, void* d_ws, size_t ws_size,
                              hipStream_t stream)
{
    const float* target = (const float*)d_in[0];  // [8192, 512]
    const float* source = (const float*)d_in[1];  // [1000, 4096]
    const float* value  = (const float*)d_in[2];  // [1000, 4096]
    const float* Wq = (const float*)d_in[3];      // [512, 1024]
    const float* bq = (const float*)d_in[4];
    const float* Wk = (const float*)d_in[5];      // [4096, 1024]
    const float* bk = (const float*)d_in[6];
    const float* Wv = (const float*)d_in[7];      // [4096, 1024]
    const float* bv = (const float*)d_in[8];
    const float* Wo = (const float*)d_in[9];      // [1024, 4096]
    const float* bo = (const float*)d_in[10];

    // d_out is fp32 [8192,4096] = 128 MB. Scratch whose lifetime ends before
    // the final GEMM lives there (61 MB). AO + WoT (read by final GEMM) -> d_ws.
    char* po = (char*)d_out;
    size_t off = 0;
    bf16* tgt_b = (bf16*)(po + off); off += (size_t)8192 * 512 * 2;   //  8 MB
    bf16* src_b = (bf16*)(po + off); off += (size_t)1024 * 4096 * 2;  //  8 MB
    bf16* val_b = (bf16*)(po + off); off += (size_t)1024 * 4096 * 2;  //  8 MB
    bf16* WqT   = (bf16*)(po + off); off += (size_t)1024 * 512 * 2;   //  1 MB
    bf16* WkT   = (bf16*)(po + off); off += (size_t)1024 * 4096 * 2;  //  8 MB
    bf16* WvT   = (bf16*)(po + off); off += (size_t)1024 * 4096 * 2;  //  8 MB
    bf16* Qb    = (bf16*)(po + off); off += (size_t)8192 * 1024 * 2;  // 16 MB
    bf16* Kb    = (bf16*)(po + off); off += (size_t)1024 * 1024 * 2;  //  2 MB
    bf16* Vt    = (bf16*)(po + off); off += (size_t)1024 * 1024 * 2;  //  2 MB = 61 MB
    char* ws = (char*)d_ws;
    bf16* AO  = (bf16*)ws;                                   // 16 MB
    bf16* WoT = (bf16*)(ws + (size_t)8192 * 1024 * 2);       //  8 MB (24 MB d_ws)

    // Fused casts: grid.y = {target, source, value}.
    cast3_f32_bf16<<<dim3(2048, 3), 256, 0, stream>>>(
        target, tgt_b, source, src_b, value, val_b);

    // Fused weight transposes (one launch, 12800 blocks).
    transpose4<<<12800, 256, 0, stream>>>(Wq, WqT, Wk, WkT, Wv, WvT, Wo, WoT);

    // Q = target @ Wq + bq   [8192,1024] bf16
    gemm_bt<<<dim3(8, 64), 256, 0, stream>>>(tgt_b, WqT, bq, Qb, 8192, 1024, 512, 512, 512, 1024, 0);
    // K = source @ Wk + bk -> Kb;  V^T = (value @ Wv + bv)^T -> Vt  (fused)
    gemm_kv<<<dim3(16, 16, 2), 256, 0, stream>>>(
        src_b, WkT, bk, Kb, val_b, WvT, bv, Vt);

    // attention -> AO [8192,1024] bf16
    flash_attn<<<dim3(64, 8), 256, 0, stream>>>(Qb, Kb, Vt, AO);

    // out = AO @ Wo + bo -> d_out FP32 [8192,4096] (nt stores; full overwrite)
    gemm_bt<<<dim3(32, 64), 256, 0, stream>>>(AO, WoT, bo, d_out, 8192, 4096, 1024, 1024, 1024, 4096, 1);

    (void)in_sizes; (void)n_in; (void)out_size; (void)ws_size;
}